// Round 2
// baseline (1003.166 us; speedup 1.0000x reference)
//
#include <hip/hip_runtime.h>

// Problem constants (fixed by the reference).
static constexpr int Mdim = 4096;
static constexpr int Kdim = 4096;
static constexpr int Ndim = 16384;
static constexpr int BM = 128, BN = 128, BK = 64;
static constexpr int TILES_N = Ndim / BN;  // 128
static constexpr int TILES_M = Mdim / BM;  // 32

typedef __attribute__((ext_vector_type(8))) short bf16x8;  // 8 bf16 = 4 VGPRs (guide §3)
typedef __attribute__((ext_vector_type(4))) float f32x4;   // MFMA C/D

// ---------- conversion helpers ----------
// fp32 -> bf16 RNE, two at a time, packed into one u32.
__device__ __forceinline__ unsigned packbf(float lo, float hi) {
  unsigned a = __builtin_bit_cast(unsigned, lo);
  unsigned b = __builtin_bit_cast(unsigned, hi);
  a += 0x7FFFu + ((a >> 16) & 1u);
  b += 0x7FFFu + ((b >> 16) & 1u);
  return (a >> 16) | (b & 0xFFFF0000u);
}

// two int32 (range [-127,127]) -> two bf16 packed in u32. Exact (|v|<=127 fits bf16 mantissa).
__device__ __forceinline__ unsigned i32x2bf(int lo, int hi) {
  float f0 = (float)lo;
  float f1 = (float)hi;
  return (__builtin_bit_cast(unsigned, f0) >> 16) |
         (__builtin_bit_cast(unsigned, f1) & 0xFFFF0000u);
}

// ---------- Path A: standalone converters (memory-bound) ----------
__global__ void cvt_x_kernel(const float4* __restrict__ in, uint4* __restrict__ out) {
  int i = blockIdx.x * 256 + threadIdx.x;   // one 16B bf16 chunk (8 elems) per thread
  float4 a = in[2 * i];
  float4 b = in[2 * i + 1];
  uint4 o;
  o.x = packbf(a.x, a.y);
  o.y = packbf(a.z, a.w);
  o.z = packbf(b.x, b.y);
  o.w = packbf(b.z, b.w);
  out[i] = o;
}

// NOTE: harness uploads ALL integer inputs as int32 ("integer -> const int*").
// weight_q is therefore N*K int32 values in [-127,127], 32 B per 8 elements.
__global__ void cvt_w_kernel(const int4* __restrict__ in, uint4* __restrict__ out) {
  int i = blockIdx.x * 256 + threadIdx.x;   // 8 int32 -> 8 bf16 per thread
  int4 a = in[2 * i];
  int4 b = in[2 * i + 1];
  uint4 o;
  o.x = i32x2bf(a.x, a.y);
  o.y = i32x2bf(a.z, a.w);
  o.z = i32x2bf(b.x, b.y);
  o.w = i32x2bf(b.z, b.w);
  out[i] = o;
}

// ---------- shared MFMA compute: swizzled LDS layout ----------
// LDS tile = 128 rows x 8 chunks of 8 bf16. Chunk (m, c) lives at slot m*8 + (c ^ (m&7)).
// Staging writes slots linearly (global_load_lds-compatible); fragment reads are
// conflict-free: 8-lane phase covers 8 disjoint 4-bank groups (XOR permutes within row).
__device__ __forceinline__ void mfma_tile(const unsigned short* As, const unsigned short* Bs,
                                          int am, int bnl, int quad, f32x4 acc[4][4]) {
#pragma unroll
  for (int ks = 0; ks < 2; ++ks) {           // two K=32 steps per BK=64
    const int c = ks * 4 + quad;             // k-chunk this quad reads
    bf16x8 af[4], bv[4];
#pragma unroll
    for (int t = 0; t < 4; ++t) {
      int ma = am + t * 16;                  // A row (m) for subtile t
      af[t] = *(const bf16x8*)(As + (ma * 8 + (c ^ (ma & 7))) * 8);
      int nb = bnl + t * 16;                 // B row (n) for subtile t
      bv[t] = *(const bf16x8*)(Bs + (nb * 8 + (c ^ (nb & 7))) * 8);
    }
#pragma unroll
    for (int mi = 0; mi < 4; ++mi)
#pragma unroll
      for (int ni = 0; ni < 4; ++ni)
        acc[mi][ni] = __builtin_amdgcn_mfma_f32_16x16x32_bf16(af[mi], bv[ni], acc[mi][ni], 0, 0, 0);
  }
}

__device__ __forceinline__ void epilogue(float* __restrict__ out,
                                         const float* __restrict__ scale,
                                         const float* __restrict__ bias,
                                         int row0, int col0, int wm, int wn, int lane,
                                         f32x4 acc[4][4]) {
  const int rbase = (lane >> 4) * 4;         // C/D: row = quad*4 + reg (m89-verified)
#pragma unroll
  for (int ni = 0; ni < 4; ++ni) {
    const int n = col0 + wn * 64 + ni * 16 + (lane & 15);  // C/D: col = lane&15
    const float sc = scale[n];
    const float bz = bias[n];
#pragma unroll
    for (int mi = 0; mi < 4; ++mi) {
      const int m = row0 + wm * 64 + mi * 16 + rbase;
      float* o = out + (long)m * Ndim + n;
#pragma unroll
      for (int r = 0; r < 4; ++r)
        o[(long)r * Ndim] = acc[mi][ni][r] * sc + bz;
    }
  }
}

// ---------- Path A GEMM: bf16 x bf16, global_load_lds staging (m97-style) ----------
__global__ __launch_bounds__(256, 2) void gemm_bf16(const unsigned short* __restrict__ A,   // [M,K] bf16
                                                    const unsigned short* __restrict__ B,   // [N,K] bf16
                                                    const float* __restrict__ scale,
                                                    const float* __restrict__ bias,
                                                    float* __restrict__ out) {
  __shared__ unsigned short As[BM * BK];  // 16 KB, swizzled slot layout
  __shared__ unsigned short Bs[BN * BK];  // 16 KB

  const int tid = threadIdx.x;
  const int lane = tid & 63;
  const int w = tid >> 6;            // wave 0..3
  const int wm = w & 1, wn = w >> 1; // 2x2 wave grid, 64x64 per wave
  const int bid = blockIdx.x;
  const int bn = bid % TILES_N;
  const int bm = bid / TILES_N;
  const int row0 = bm * BM, col0 = bn * BN;
  const int j4 = w * 4;

  // Per-lane global source for each of this wave's 4 staging calls (slot = call*64+lane).
  const unsigned short* ag[4];
  const unsigned short* bg[4];
#pragma unroll
  for (int i = 0; i < 4; ++i) {
    int s = (j4 + i) * 64 + lane;
    int m = s >> 3, cs = s & 7, c = cs ^ (m & 7);   // inverse of read-side swizzle
    ag[i] = A + (long)(row0 + m) * Kdim + c * 8;
    bg[i] = B + (long)(col0 + m) * Kdim + c * 8;
  }

  f32x4 acc[4][4];
#pragma unroll
  for (int mi = 0; mi < 4; ++mi)
#pragma unroll
    for (int ni = 0; ni < 4; ++ni) acc[mi][ni] = (f32x4){0.f, 0.f, 0.f, 0.f};

  const int am = wm * 64 + (lane & 15);
  const int bnl = wn * 64 + (lane & 15);
  const int quad = lane >> 4;

  for (int kt = 0; kt < Kdim / BK; ++kt) {
    __syncthreads();  // all waves done reading LDS from previous iter
#pragma unroll
    for (int i = 0; i < 4; ++i) {
      __builtin_amdgcn_global_load_lds(
          (const __attribute__((address_space(1))) void*)(ag[i] + kt * BK),
          (__attribute__((address_space(3))) void*)(&As[(j4 + i) * 512]), 16, 0, 0);
      __builtin_amdgcn_global_load_lds(
          (const __attribute__((address_space(1))) void*)(bg[i] + kt * BK),
          (__attribute__((address_space(3))) void*)(&Bs[(j4 + i) * 512]), 16, 0, 0);
    }
    __syncthreads();  // vmcnt(0) drain: tiles resident
    mfma_tile(As, Bs, am, bnl, quad, acc);
  }
  epilogue(out, scale, bias, row0, col0, wm, wn, lane, acc);
}

// ---------- Path B GEMM: fused fp32/int32 -> bf16 conversion + ds_write staging ----------
__global__ __launch_bounds__(256, 2) void gemm_fused(const float* __restrict__ X,   // [M,K] fp32
                                                     const int* __restrict__ Wq,    // [N,K] int32
                                                     const float* __restrict__ scale,
                                                     const float* __restrict__ bias,
                                                     float* __restrict__ out) {
  __shared__ unsigned short As[BM * BK];
  __shared__ unsigned short Bs[BN * BK];

  const int tid = threadIdx.x;
  const int lane = tid & 63;
  const int w = tid >> 6;
  const int wm = w & 1, wn = w >> 1;
  const int bid = blockIdx.x;
  const int bn = bid % TILES_N;
  const int bm = bid / TILES_N;
  const int row0 = bm * BM, col0 = bn * BN;

  // Each thread fills 4 A-slots and 4 B-slots per K-tile: slot s = i*256 + tid.
  int slot[4];
  long aoff[4], boff[4];
#pragma unroll
  for (int i = 0; i < 4; ++i) {
    int s = i * 256 + tid;
    int m = s >> 3, cs = s & 7, c = cs ^ (m & 7);
    slot[i] = s;
    aoff[i] = (long)(row0 + m) * Kdim + c * 8;
    boff[i] = (long)(col0 + m) * Kdim + c * 8;
  }

  f32x4 acc[4][4];
#pragma unroll
  for (int mi = 0; mi < 4; ++mi)
#pragma unroll
    for (int ni = 0; ni < 4; ++ni) acc[mi][ni] = (f32x4){0.f, 0.f, 0.f, 0.f};

  const int am = wm * 64 + (lane & 15);
  const int bnl = wn * 64 + (lane & 15);
  const int quad = lane >> 4;

  for (int kt = 0; kt < Kdim / BK; ++kt) {
    uint4 aw[4], bw[4];
#pragma unroll
    for (int i = 0; i < 4; ++i) {
      const float4* ap = (const float4*)(X + aoff[i] + kt * BK);
      float4 a0 = ap[0];
      float4 a1 = ap[1];
      aw[i].x = packbf(a0.x, a0.y);
      aw[i].y = packbf(a0.z, a0.w);
      aw[i].z = packbf(a1.x, a1.y);
      aw[i].w = packbf(a1.z, a1.w);
      const int4* bp = (const int4*)(Wq + boff[i] + kt * BK);  // int32 weights!
      int4 b0 = bp[0];
      int4 b1 = bp[1];
      bw[i].x = i32x2bf(b0.x, b0.y);
      bw[i].y = i32x2bf(b0.z, b0.w);
      bw[i].z = i32x2bf(b1.x, b1.y);
      bw[i].w = i32x2bf(b1.z, b1.w);
    }
    __syncthreads();
#pragma unroll
    for (int i = 0; i < 4; ++i) {
      *(uint4*)(&As[slot[i] * 8]) = aw[i];
      *(uint4*)(&Bs[slot[i] * 8]) = bw[i];
    }
    __syncthreads();
    mfma_tile(As, Bs, am, bnl, quad, acc);
  }
  epilogue(out, scale, bias, row0, col0, wm, wn, lane, acc);
}

extern "C" void kernel_launch(void* const* d_in, const int* in_sizes, int n_in,
                              void* d_out, int out_size, void* d_ws, size_t ws_size,
                              hipStream_t stream) {
  const float* x = (const float*)d_in[0];
  const int* wq = (const int*)d_in[1];      // int8 weights uploaded as int32 [N*K]
  const float* wscale = (const float*)d_in[2];
  const float* wbias = (const float*)d_in[3];
  float* out = (float*)d_out;

  const size_t needA = ((size_t)Mdim * Kdim + (size_t)Ndim * Kdim) * 2;  // 160 MB bf16
  if (ws_size >= needA) {
    // Path A: pre-convert to bf16 in workspace, then global_load_lds GEMM.
    unsigned short* xb = (unsigned short*)d_ws;
    unsigned short* wb = xb + (size_t)Mdim * Kdim;
    cvt_x_kernel<<<(Mdim * Kdim) / 8 / 256, 256, 0, stream>>>((const float4*)x, (uint4*)xb);
    cvt_w_kernel<<<(Ndim / 256) * (Kdim / 8), 256, 0, stream>>>((const int4*)wq, (uint4*)wb);
    gemm_bf16<<<TILES_M * TILES_N, 256, 0, stream>>>(xb, wb, wscale, wbias, out);
  } else {
    // Path B: fused conversion inside the GEMM (no workspace dependency).
    gemm_fused<<<TILES_M * TILES_N, 256, 0, stream>>>(x, wq, wscale, wbias, out);
  }
}